// Round 8
// baseline (927.156 us; speedup 1.0000x reference)
//
#include <hip/hip_runtime.h>

// Bidirectional LSTM, I=7, H=64, O=3, B=256, T=2048.
// Output = concat(h_fwd after T steps, h_bwd after ONE step on x[T-1]) @ W_lin^T + b_lin.
//
// Round-8: identical to round 7 (one wave per batch elem, barrier-free,
// bpermute pair-gather + DPP wave_ror rotation, v_dot2_f32_f16) EXCEPT:
// whh is held in 8x ext_vector_type(16) uint (b512 register tuples) to force
// the register allocator to keep all 128 weight dwords in contiguous ARCH
// VGPRs. Rounds 5-7 allocated only 132-148 VGPRs against ~175 live values,
// i.e. part of whh was parked in AGPRs with per-use v_accvgpr_read bloat
// (suspected ~2x instruction-count inflation, VALUBusy ~85% on the busy SIMD).
// This round discriminates parking (H1) vs dot2-half-rate (H2).

typedef __fp16 half2v __attribute__((ext_vector_type(2)));
typedef unsigned int u16v __attribute__((ext_vector_type(16)));

#define TSEQ 2048
#define IN   7

__device__ __forceinline__ float fast_sigmoid(float x) {
    float e = __builtin_amdgcn_exp2f(-1.4426950408889634f * x);   // 2^(-x*log2e)
    return __builtin_amdgcn_rcpf(1.0f + e);
}
// tanh(x) = 2/(1+exp2(-2x*log2e)) - 1 ; exp2 saturates to 0/inf -> +-1, no clamp
__device__ __forceinline__ float fast_tanh(float x) {
    float e = __builtin_amdgcn_exp2f(-2.8853900817779268f * x);
    return fmaf(2.0f, __builtin_amdgcn_rcpf(1.0f + e), -1.0f);
}
__device__ __forceinline__ half2v h2i(int v)    { return __builtin_bit_cast(half2v, v); }
__device__ __forceinline__ int    i2h(half2v v) { return __builtin_bit_cast(int, v); }
__device__ __forceinline__ half2v pk(float a, float b) { return __builtin_amdgcn_cvt_pkrtz(a, b); }
__device__ __forceinline__ float  dot2(half2v a, half2v b, float c) {
    return __builtin_amdgcn_fdot2(a, b, c, false);
}
// full-wave rotate by 1 lane (VALU DPP, no SGPR, no LDS)
__device__ __forceinline__ int wror1_i(int v) {
    return __builtin_amdgcn_mov_dpp(v, 0x13C, 0xF, 0xF, false);
}

__global__ __launch_bounds__(64)
__attribute__((amdgpu_waves_per_eu(1, 1)))
void bilstm_kernel(const float* __restrict__ x,      // [B, T, I]
                   const float* __restrict__ Wih_f,  // [256, 7]
                   const float* __restrict__ Whh_f,  // [256, 64]
                   const float* __restrict__ bih_f,  // [256]
                   const float* __restrict__ bhh_f,  // [256]
                   const float* __restrict__ Wih_b,  // [256, 7]
                   const float* __restrict__ bih_b,  // [256]
                   const float* __restrict__ bhh_b,  // [256]
                   const float* __restrict__ Wlin,   // [3, 128]
                   const float* __restrict__ blin,   // [3]
                   float* __restrict__ out)          // [B, 3]
{
    __shared__ __align__(16) __fp16 xh[TSEQ * 8 + 64];   // ~33 KB

    const int lane = threadIdx.x;      // 0..63, one wave
    const int b    = blockIdx.x;

    // ---- stage x as f16, layout [t][8] = {x0..x6, 1.0} (pad carries bias) ----
    const float* xb = x + (size_t)b * (TSEQ * IN);
    for (int t = lane; t < TSEQ; t += 64) {
        const float* xp = xb + t * IN;
        int4 w;
        w.x = i2h(pk(xp[0], xp[1]));
        w.y = i2h(pk(xp[2], xp[3]));
        w.z = i2h(pk(xp[4], xp[5]));
        w.w = i2h(pk(xp[6], 1.0f));    // pad = 1.0 -> dot2 with (w6, bias)
        *(int4*)&xh[t * 8] = w;
    }

    // ---- probe wave_ror direction: after 1 ror, lane l holds old lane (l+dv)&63 ----
    const int dv = __builtin_amdgcn_readfirstlane(wror1_i(lane));   // 1 or 63

    // ---- pack forward weights: lane l owns rows l, 64+l, 128+l, 192+l ----
    // Weight pairs pre-gathered in ROTATED order (iteration r sees pair
    // ((lane + r*dv) & 31)), stored across 8 b512 vector registers so the
    // allocator keeps them in contiguous arch VGPRs (no AGPR parking).
    half2v wih[4][4];
    u16v wc[8];            // 128 dwords: wc[idx>>4][idx&15], idx = g*32 + r
    #pragma unroll
    for (int g = 0; g < 4; ++g) {
        const int r0 = g * 64 + lane;
        const float biasg = bih_f[r0] + bhh_f[r0];
        const float* wr = Wih_f + r0 * IN;
        wih[g][0] = pk(wr[0], wr[1]);
        wih[g][1] = pk(wr[2], wr[3]);
        wih[g][2] = pk(wr[4], wr[5]);
        wih[g][3] = pk(wr[6], biasg);          // bias rides the 1.0 pad
        const float* hr = Whh_f + r0 * 64;
        #pragma unroll
        for (int r = 0; r < 32; ++r) {
            const int p   = (lane + r * dv) & 31;
            const int idx = g * 32 + r;
            wc[idx >> 4][idx & 15] = (unsigned)i2h(pk(hr[2 * p], hr[2 * p + 1]));
        }
    }

    // bpermute byte-addresses for the pair gather (loop-invariant)
    const int adrE = ((lane & 31) * 2) * 4;        // lane of h[2m]
    const int adrO = ((lane & 31) * 2 + 1) * 4;    // lane of h[2m+1]

    float h = 0.0f, c = 0.0f;

    int4 xcur = *(const int4*)&xh[0];   // x_0 (waits on staging via lgkmcnt)

    // ---- forward recurrence: barrier-free ----
    for (int t = 0; t < TSEQ; ++t) {
        // gather h into packed pairs: lane l <- (h[2m], h[2m+1]), m = l&31
        const int hi = __float_as_int(h);
        const float hE = __int_as_float(__builtin_amdgcn_ds_bpermute(adrE, hi));
        const float hO = __int_as_float(__builtin_amdgcn_ds_bpermute(adrO, hi));
        int hp = i2h(pk(hE, hO));

        const int4 xq = xcur;
        xcur = *(const int4*)&xh[((t + 1) & (TSEQ - 1)) * 8];   // prefetch next step

        // input projection + bias (8 values incl. 1.0 pad) — independent of the
        // bpermute, covers its latency
        float z0, z1, z2, z3;
        {
            const half2v x0 = h2i(xq.x), x1 = h2i(xq.y), x2 = h2i(xq.z), x3 = h2i(xq.w);
            z0 = dot2(x0, wih[0][0], 0.0f);  z1 = dot2(x0, wih[1][0], 0.0f);
            z2 = dot2(x0, wih[2][0], 0.0f);  z3 = dot2(x0, wih[3][0], 0.0f);
            z0 = dot2(x1, wih[0][1], z0);    z1 = dot2(x1, wih[1][1], z1);
            z2 = dot2(x1, wih[2][1], z2);    z3 = dot2(x1, wih[3][1], z3);
            z0 = dot2(x2, wih[0][2], z0);    z1 = dot2(x2, wih[1][2], z1);
            z2 = dot2(x2, wih[2][2], z2);    z3 = dot2(x2, wih[3][2], z3);
            z0 = dot2(x3, wih[0][3], z0);    z1 = dot2(x3, wih[1][3], z1);
            z2 = dot2(x3, wih[2][3], z2);    z3 = dot2(x3, wih[3][3], z3);
        }

        // W_hh . h : 32 rotations of the packed-pair register, 4 dot2 each
        #pragma unroll
        for (int r = 0; r < 32; ++r) {
            const half2v pb = h2i(hp);
            const int i0 = 0 * 32 + r, i1 = 1 * 32 + r, i2 = 2 * 32 + r, i3 = 3 * 32 + r;
            z0 = dot2(pb, h2i((int)wc[i0 >> 4][i0 & 15]), z0);
            z1 = dot2(pb, h2i((int)wc[i1 >> 4][i1 & 15]), z1);
            z2 = dot2(pb, h2i((int)wc[i2 >> 4][i2 & 15]), z2);
            z3 = dot2(pb, h2i((int)wc[i3 >> 4][i3 & 15]), z3);
            if (r < 31) hp = wror1_i(hp);
        }

        const float ai = fast_sigmoid(z0);
        const float af = fast_sigmoid(z1);
        const float ag = fast_tanh(z2);
        const float ao = fast_sigmoid(z3);
        c = fmaf(af, c, ai * ag);
        h = ao * fast_tanh(c);     // lane l holds h[l]; feeds next step's gather
    }

    // ---- backward direction: ONE step on x[T-1] from zero state ----
    float hbv;
    {
        const int4 xq = *(const int4*)&xh[(TSEQ - 1) * 8];
        const half2v x0 = h2i(xq.x), x1 = h2i(xq.y), x2 = h2i(xq.z), x3 = h2i(xq.w);
        float zb[4];
        #pragma unroll
        for (int g = 0; g < 4; ++g) {
            const int r0 = g * 64 + lane;
            const float* wr = Wih_b + r0 * IN;
            float z = bih_b[r0] + bhh_b[r0];
            z = dot2(x0, pk(wr[0], wr[1]), z);
            z = dot2(x1, pk(wr[2], wr[3]), z);
            z = dot2(x2, pk(wr[4], wr[5]), z);
            z = dot2(x3, pk(wr[6], 0.0f), z);   // pad=1.0 times 0 weight = 0
            zb[g] = z;
        }
        const float ai = fast_sigmoid(zb[0]);
        const float ag = fast_tanh(zb[2]);
        const float ao = fast_sigmoid(zb[3]);
        hbv = ao * fast_tanh(ai * ag);    // c0 = 0 -> c = i*g
    }

    // ---- final linear via per-lane partials + wave reduction ----
    float s0 = fmaf(h, Wlin[0 * 128 + lane], hbv * Wlin[0 * 128 + 64 + lane]);
    float s1 = fmaf(h, Wlin[1 * 128 + lane], hbv * Wlin[1 * 128 + 64 + lane]);
    float s2 = fmaf(h, Wlin[2 * 128 + lane], hbv * Wlin[2 * 128 + 64 + lane]);
    #pragma unroll
    for (int off = 32; off > 0; off >>= 1) {
        s0 += __shfl_xor(s0, off, 64);
        s1 += __shfl_xor(s1, off, 64);
        s2 += __shfl_xor(s2, off, 64);
    }
    if (lane == 0) {
        out[b * 3 + 0] = s0 + blin[0];
        out[b * 3 + 1] = s1 + blin[1];
        out[b * 3 + 2] = s2 + blin[2];
    }
}

extern "C" void kernel_launch(void* const* d_in, const int* in_sizes, int n_in,
                              void* d_out, int out_size, void* d_ws, size_t ws_size,
                              hipStream_t stream) {
    const float* x      = (const float*)d_in[0];
    const float* Wih_f  = (const float*)d_in[1];
    const float* Whh_f  = (const float*)d_in[2];
    const float* bih_f  = (const float*)d_in[3];
    const float* bhh_f  = (const float*)d_in[4];
    const float* Wih_b  = (const float*)d_in[5];
    // d_in[6] = W_hh_bwd: unused (backward runs exactly one step from h0=0)
    const float* bih_b  = (const float*)d_in[7];
    const float* bhh_b  = (const float*)d_in[8];
    const float* Wlin   = (const float*)d_in[9];
    const float* blin   = (const float*)d_in[10];
    float* out = (float*)d_out;

    bilstm_kernel<<<256, 64, 0, stream>>>(x, Wih_f, Whh_f, bih_f, bhh_f,
                                          Wih_b, bih_b, bhh_b, Wlin, blin, out);
}